// Round 1
// baseline (322.634 us; speedup 1.0000x reference)
//
#include <hip/hip_runtime.h>

// ---------------------------------------------------------------------------
// 2-layer GCN on MI355X.
// Pipeline per launch (all on `stream`, rebuilt every call — ws is re-poisoned):
//   1. zero cnt/fill
//   2. count in-degree at dst (int atomics)
//   3. dinv[i] = rsqrt(deg+1)  (self-loop included)
//   4. exclusive scan of counts -> CSR row_ptr (3-kernel scan, N=50000)
//   5. scatter edges into sorted_src by dst (atomic fill)
//   6. GEMM  h1 = X @ W1           (fp32, LDS-tiled, 128x128 tile)
//   7. AGG   z1 = relu(Ahat h1 + b1)   (1 wave / node, CSR gather)
//   8. GEMM  h2 = z1 @ W2
//   9. AGG   out = Ahat h2 + b2
// ---------------------------------------------------------------------------

__global__ __launch_bounds__(256) void zero_kernel(int* __restrict__ p, int n) {
    int i = blockIdx.x * 256 + threadIdx.x;
    if (i < n) p[i] = 0;
}

__global__ __launch_bounds__(256) void count_kernel(const int* __restrict__ dst,
                                                    int* __restrict__ cnt, int E) {
    int e = blockIdx.x * 256 + threadIdx.x;
    if (e < E) atomicAdd(&cnt[dst[e]], 1);
}

__global__ __launch_bounds__(256) void dinv_kernel(const int* __restrict__ cnt,
                                                   float* __restrict__ dinv, int N) {
    int i = blockIdx.x * 256 + threadIdx.x;
    if (i < N) dinv[i] = rsqrtf((float)(cnt[i] + 1));  // +1 = self loop
}

// --- 3-kernel exclusive scan (N <= 256*256) --------------------------------
__global__ __launch_bounds__(256) void scan1_kernel(const int* __restrict__ cnt,
                                                    int* __restrict__ row_ptr,
                                                    int* __restrict__ blksum, int N) {
    __shared__ int sm[256];
    int i = blockIdx.x * 256 + threadIdx.x;
    int v = (i < N) ? cnt[i] : 0;
    sm[threadIdx.x] = v;
    __syncthreads();
    for (int off = 1; off < 256; off <<= 1) {
        int t = (threadIdx.x >= off) ? sm[threadIdx.x - off] : 0;
        __syncthreads();
        sm[threadIdx.x] += t;
        __syncthreads();
    }
    if (i < N) row_ptr[i] = sm[threadIdx.x] - v;  // exclusive
    if (threadIdx.x == 255) blksum[blockIdx.x] = sm[255];
}

__global__ __launch_bounds__(256) void scan2_kernel(int* __restrict__ blksum, int nb) {
    __shared__ int sm[256];
    int i = threadIdx.x;
    int v = (i < nb) ? blksum[i] : 0;
    sm[i] = v;
    __syncthreads();
    for (int off = 1; off < 256; off <<= 1) {
        int t = (i >= off) ? sm[i - off] : 0;
        __syncthreads();
        sm[i] += t;
        __syncthreads();
    }
    if (i < nb) blksum[i] = sm[i] - v;  // exclusive over block totals
}

__global__ __launch_bounds__(256) void scan3_kernel(int* __restrict__ row_ptr,
                                                    const int* __restrict__ blksum,
                                                    int N, int E) {
    int i = blockIdx.x * 256 + threadIdx.x;
    if (i < N) row_ptr[i] += blksum[blockIdx.x];
    if (i == 0) row_ptr[N] = E;
}

__global__ __launch_bounds__(256) void scatter_kernel(const int* __restrict__ src,
                                                      const int* __restrict__ dst,
                                                      const int* __restrict__ row_ptr,
                                                      int* __restrict__ fill,
                                                      int* __restrict__ ssrc, int E) {
    int e = blockIdx.x * 256 + threadIdx.x;
    if (e < E) {
        int d = dst[e];
        int p = row_ptr[d] + atomicAdd(&fill[d], 1);
        ssrc[p] = src[e];
    }
}

// --- fp32 GEMM: C[N,M] = A[N,128] @ W[128,M], tile 128 rows x M cols -------
// block = 256 threads = (tx 0..15) x (ty 0..15); thread owns 8 rows x (M/16) cols.
template <int M>
__global__ __launch_bounds__(256) void gemm_kernel(const float* __restrict__ A,
                                                   const float* __restrict__ W,
                                                   float* __restrict__ C, int N) {
    constexpr int K = 128, KC = 32, AS_LD = 132;
    constexpr int TN = M / 16;
    __shared__ float As[KC][AS_LD];  // transposed: As[k][row]
    __shared__ float Bs[KC][M];

    int tid = threadIdx.x;
    int tx = tid & 15;
    int ty = tid >> 4;
    int row0 = blockIdx.x * 128;

    float acc[8][TN];
#pragma unroll
    for (int i = 0; i < 8; ++i)
#pragma unroll
        for (int j = 0; j < TN; ++j) acc[i][j] = 0.f;

    for (int kc = 0; kc < K; kc += KC) {
        // stage A chunk (128 rows x 32 k), transposed into LDS
#pragma unroll
        for (int f = 0; f < 4; ++f) {
            int q = tid + 256 * f;      // 0..1023 float4s
            int r = q >> 3;             // tile row 0..127
            int kq = (q & 7) << 2;      // k offset 0..28
            int grow = row0 + r;
            float4 v = make_float4(0.f, 0.f, 0.f, 0.f);
            if (grow < N) v = *(const float4*)(A + (size_t)grow * K + kc + kq);
            As[kq + 0][r] = v.x;
            As[kq + 1][r] = v.y;
            As[kq + 2][r] = v.z;
            As[kq + 3][r] = v.w;
        }
        // stage B chunk (32 k x M cols), straight copy
        constexpr int BQ = KC * M / 4;
#pragma unroll
        for (int f = 0; f < BQ / 256; ++f) {
            int q = tid + 256 * f;
            int r = q / (M / 4);
            int c4 = (q % (M / 4)) << 2;
            *(float4*)(&Bs[r][c4]) = *(const float4*)(W + (size_t)(kc + r) * M + c4);
        }
        __syncthreads();

#pragma unroll
        for (int k = 0; k < KC; ++k) {
            float a[8], b[TN];
#pragma unroll
            for (int i = 0; i < 8; ++i) a[i] = As[k][ty * 8 + i];
#pragma unroll
            for (int j = 0; j < TN; ++j) b[j] = Bs[k][tx * TN + j];
#pragma unroll
            for (int i = 0; i < 8; ++i)
#pragma unroll
                for (int j = 0; j < TN; ++j) acc[i][j] += a[i] * b[j];
        }
        __syncthreads();
    }

#pragma unroll
    for (int i = 0; i < 8; ++i) {
        int grow = row0 + ty * 8 + i;
        if (grow < N) {
#pragma unroll
            for (int j = 0; j < TN; j += 4) {
                *(float4*)(C + (size_t)grow * M + tx * TN + j) =
                    make_float4(acc[i][j], acc[i][j + 1], acc[i][j + 2], acc[i][j + 3]);
            }
        }
    }
}

// --- CSR aggregation: one wave per node ------------------------------------
// out[i] = dinv[i] * ( dinv[i]*h[i] + sum_{e: dst=i} dinv[src]*h[src] ) + b
template <int M, bool RELU>
__global__ __launch_bounds__(256) void agg_kernel(const float* __restrict__ h,
                                                  const int* __restrict__ row_ptr,
                                                  const int* __restrict__ ssrc,
                                                  const float* __restrict__ dinv,
                                                  const float* __restrict__ bias,
                                                  float* __restrict__ out, int N) {
    int node = __builtin_amdgcn_readfirstlane((int)(blockIdx.x * 4 + (threadIdx.x >> 6)));
    if (node >= N) return;
    int lane = threadIdx.x & 63;
    float di = dinv[node];
    int beg = row_ptr[node];
    int end = row_ptr[node + 1];

    if constexpr (M == 128) {
        const float2* hp = (const float2*)h;
        float2 hv = hp[(size_t)node * 64 + lane];
        float ax = di * hv.x, ay = di * hv.y;
        int j = beg;
        for (; j + 3 < end; j += 4) {
            int s0 = ssrc[j], s1 = ssrc[j + 1], s2 = ssrc[j + 2], s3 = ssrc[j + 3];
            float d0 = dinv[s0], d1 = dinv[s1], d2 = dinv[s2], d3 = dinv[s3];
            float2 v0 = hp[(size_t)s0 * 64 + lane];
            float2 v1 = hp[(size_t)s1 * 64 + lane];
            float2 v2 = hp[(size_t)s2 * 64 + lane];
            float2 v3 = hp[(size_t)s3 * 64 + lane];
            ax += d0 * v0.x + d1 * v1.x + d2 * v2.x + d3 * v3.x;
            ay += d0 * v0.y + d1 * v1.y + d2 * v2.y + d3 * v3.y;
        }
        for (; j < end; ++j) {
            int s = ssrc[j];
            float ds = dinv[s];
            float2 v = hp[(size_t)s * 64 + lane];
            ax += ds * v.x;
            ay += ds * v.y;
        }
        ax = ax * di + bias[2 * lane];
        ay = ay * di + bias[2 * lane + 1];
        if (RELU) {
            ax = fmaxf(ax, 0.f);
            ay = fmaxf(ay, 0.f);
        }
        ((float2*)out)[(size_t)node * 64 + lane] = make_float2(ax, ay);
    } else {  // M == 64, one float per lane
        float acc = di * h[(size_t)node * 64 + lane];
        int j = beg;
        for (; j + 3 < end; j += 4) {
            int s0 = ssrc[j], s1 = ssrc[j + 1], s2 = ssrc[j + 2], s3 = ssrc[j + 3];
            float d0 = dinv[s0], d1 = dinv[s1], d2 = dinv[s2], d3 = dinv[s3];
            acc += d0 * h[(size_t)s0 * 64 + lane] + d1 * h[(size_t)s1 * 64 + lane] +
                   d2 * h[(size_t)s2 * 64 + lane] + d3 * h[(size_t)s3 * 64 + lane];
        }
        for (; j < end; ++j) {
            int s = ssrc[j];
            acc += dinv[s] * h[(size_t)s * 64 + lane];
        }
        acc = acc * di + bias[lane];
        if (RELU) acc = fmaxf(acc, 0.f);
        out[(size_t)node * 64 + lane] = acc;
    }
}

extern "C" void kernel_launch(void* const* d_in, const int* in_sizes, int n_in,
                              void* d_out, int out_size, void* d_ws, size_t ws_size,
                              hipStream_t stream) {
    const float* x = (const float*)d_in[0];
    const int* eidx = (const int*)d_in[1];
    const float* W1 = (const float*)d_in[2];
    const float* b1 = (const float*)d_in[3];
    const float* W2 = (const float*)d_in[4];
    const float* b2 = (const float*)d_in[5];
    float* out = (float*)d_out;

    const int N = in_sizes[0] / 128;
    const int E = in_sizes[1] / 2;
    const int* src = eidx;       // edge_index[0]
    const int* dst = eidx + E;   // edge_index[1]

    char* ws = (char*)d_ws;
    size_t off = 0;
    auto alloc = [&](size_t bytes) -> char* {
        char* p = ws + off;
        off = (off + bytes + 255) & ~(size_t)255;
        return p;
    };
    int* cnt = (int*)alloc((size_t)N * 4);
    int* fill = (int*)alloc((size_t)N * 4);
    int* row_ptr = (int*)alloc((size_t)(N + 1) * 4);
    int* blksum = (int*)alloc(256 * 4);
    int* ssrc = (int*)alloc((size_t)E * 4);
    float* dinv = (float*)alloc((size_t)N * 4);
    float* bufA = (float*)alloc((size_t)N * 128 * 4);
    float* bufB = (float*)alloc((size_t)N * 128 * 4);

    const int nbN = (N + 255) / 256;
    const int nbE = (E + 255) / 256;

    zero_kernel<<<nbN, 256, 0, stream>>>(cnt, N);
    zero_kernel<<<nbN, 256, 0, stream>>>(fill, N);
    count_kernel<<<nbE, 256, 0, stream>>>(dst, cnt, E);
    dinv_kernel<<<nbN, 256, 0, stream>>>(cnt, dinv, N);
    scan1_kernel<<<nbN, 256, 0, stream>>>(cnt, row_ptr, blksum, N);
    scan2_kernel<<<1, 256, 0, stream>>>(blksum, nbN);
    scan3_kernel<<<nbN, 256, 0, stream>>>(row_ptr, blksum, N, E);
    scatter_kernel<<<nbE, 256, 0, stream>>>(src, dst, row_ptr, fill, ssrc, E);

    const int gb = (N + 127) / 128;
    gemm_kernel<128><<<gb, 256, 0, stream>>>(x, W1, bufA, N);
    agg_kernel<128, true><<<(N + 3) / 4, 256, 0, stream>>>(bufA, row_ptr, ssrc, dinv, b1, bufB, N);
    gemm_kernel<64><<<gb, 256, 0, stream>>>(bufB, W2, bufA, N);
    agg_kernel<64, false><<<(N + 3) / 4, 256, 0, stream>>>(bufA, row_ptr, ssrc, dinv, b2, out, N);
}

// Round 2
// 269.610 us; speedup vs baseline: 1.1967x; 1.1967x over previous
//
#include <hip/hip_runtime.h>
#include <hip/hip_bf16.h>

// ---------------------------------------------------------------------------
// 2-layer GCN on MI355X, round 2.
//   - CSR build via counting sort (int atomics only)
//   - GEMMs: fp32 compute, 64-row tiles, conflict-free LDS, bf16 output
//   - Aggregation: 1 wave/node, gathers bf16 rows (half the bytes of r1),
//     edge payload (src, dinv[src]) packed int2 so norms stream sequentially
// ---------------------------------------------------------------------------

__device__ __forceinline__ float bf_lo(unsigned u) { return __uint_as_float(u << 16); }
__device__ __forceinline__ float bf_hi(unsigned u) { return __uint_as_float(u & 0xffff0000u); }
__device__ __forceinline__ unsigned short f2bf(float f) {
    return (unsigned short)(__bfloat16_as_ushort(__float2bfloat16(f)));
}

__global__ __launch_bounds__(256) void zero2_kernel(int* __restrict__ a,
                                                    int* __restrict__ b, int n) {
    int i = blockIdx.x * 256 + threadIdx.x;
    if (i < n) { a[i] = 0; b[i] = 0; }
}

__global__ __launch_bounds__(256) void count_kernel(const int* __restrict__ dst,
                                                    int* __restrict__ cnt, int E) {
    int e = blockIdx.x * 256 + threadIdx.x;
    if (e < E) atomicAdd(&cnt[dst[e]], 1);
}

// exclusive scan pass 1 + fused dinv = rsqrt(deg+1)
__global__ __launch_bounds__(256) void scan1_kernel(const int* __restrict__ cnt,
                                                    int* __restrict__ row_ptr,
                                                    int* __restrict__ blksum,
                                                    float* __restrict__ dinv, int N) {
    __shared__ int sm[256];
    int i = blockIdx.x * 256 + threadIdx.x;
    int v = (i < N) ? cnt[i] : 0;
    if (i < N) dinv[i] = rsqrtf((float)(v + 1));
    sm[threadIdx.x] = v;
    __syncthreads();
    for (int off = 1; off < 256; off <<= 1) {
        int t = (threadIdx.x >= off) ? sm[threadIdx.x - off] : 0;
        __syncthreads();
        sm[threadIdx.x] += t;
        __syncthreads();
    }
    if (i < N) row_ptr[i] = sm[threadIdx.x] - v;
    if (threadIdx.x == 255) blksum[blockIdx.x] = sm[255];
}

__global__ __launch_bounds__(256) void scan2_kernel(int* __restrict__ blksum, int nb) {
    __shared__ int sm[256];
    int i = threadIdx.x;
    int v = (i < nb) ? blksum[i] : 0;
    sm[i] = v;
    __syncthreads();
    for (int off = 1; off < 256; off <<= 1) {
        int t = (i >= off) ? sm[i - off] : 0;
        __syncthreads();
        sm[i] += t;
        __syncthreads();
    }
    if (i < nb) blksum[i] = sm[i] - v;
}

__global__ __launch_bounds__(256) void scan3_kernel(int* __restrict__ row_ptr,
                                                    const int* __restrict__ blksum,
                                                    int N, int E) {
    int i = blockIdx.x * 256 + threadIdx.x;
    if (i < N) row_ptr[i] += blksum[blockIdx.x];
    if (i == 0) row_ptr[N] = E;
}

// scatter edge -> CSR slot; payload = (src, bits(dinv[src]))
__global__ __launch_bounds__(256) void scatter_kernel(const int* __restrict__ src,
                                                      const int* __restrict__ dst,
                                                      const int* __restrict__ row_ptr,
                                                      const float* __restrict__ dinv,
                                                      int* __restrict__ fill,
                                                      int2* __restrict__ spd, int E) {
    int e = blockIdx.x * 256 + threadIdx.x;
    if (e < E) {
        int s = src[e];
        int d = dst[e];
        int p = row_ptr[d] + atomicAdd(&fill[d], 1);
        spd[p] = make_int2(s, __float_as_int(dinv[s]));
    }
}

// --- fp32 GEMM: C[N,M](bf16) = A[N,128](fp32) @ W[128,M](fp32) -------------
// 64-row tile, 256 threads: tx=tid&15 owns M/16 cols, ty=tid>>4 owns 4 rows.
template <int M>
__global__ __launch_bounds__(256) void gemm_kernel(const float* __restrict__ A,
                                                   const float* __restrict__ W,
                                                   unsigned short* __restrict__ C,
                                                   int N) {
    constexpr int K = 128, KC = 32, TN = M / 16;
    __shared__ float As[64][33];   // row-major, stride 33: <=2-way write, 0-conflict read
    __shared__ float Bs[KC][M];

    int tid = threadIdx.x;
    int tx = tid & 15;
    int ty = tid >> 4;
    int row0 = blockIdx.x * 64;

    float acc[4][TN];
#pragma unroll
    for (int i = 0; i < 4; ++i)
#pragma unroll
        for (int j = 0; j < TN; ++j) acc[i][j] = 0.f;

    for (int kc = 0; kc < K; kc += KC) {
        // stage A: 64 rows x 32 k = 512 float4, 2 per thread
#pragma unroll
        for (int f = 0; f < 2; ++f) {
            int q = tid + 256 * f;
            int r = q >> 3;
            int kq = (q & 7) << 2;
            int grow = row0 + r;
            float4 v = make_float4(0.f, 0.f, 0.f, 0.f);
            if (grow < N) v = *(const float4*)(A + (size_t)grow * K + kc + kq);
            As[r][kq + 0] = v.x;
            As[r][kq + 1] = v.y;
            As[r][kq + 2] = v.z;
            As[r][kq + 3] = v.w;
        }
        // stage B: 32 x M floats
        constexpr int BQ = KC * M / 4;
#pragma unroll
        for (int f = 0; f < BQ / 256; ++f) {
            int q = tid + 256 * f;
            int r = q / (M / 4);
            int c4 = (q % (M / 4)) << 2;
            *(float4*)(&Bs[r][c4]) = *(const float4*)(W + (size_t)(kc + r) * M + c4);
        }
        __syncthreads();

#pragma unroll
        for (int k = 0; k < KC; ++k) {
            float a[4], b[TN];
#pragma unroll
            for (int i = 0; i < 4; ++i) a[i] = As[ty * 4 + i][k];
#pragma unroll
            for (int j = 0; j < TN; ++j) b[j] = Bs[k][tx * TN + j];
#pragma unroll
            for (int i = 0; i < 4; ++i)
#pragma unroll
                for (int j = 0; j < TN; ++j) acc[i][j] += a[i] * b[j];
        }
        __syncthreads();
    }

    // epilogue: pack bf16, vector store
#pragma unroll
    for (int i = 0; i < 4; ++i) {
        int grow = row0 + ty * 4 + i;
        if (grow < N) {
            unsigned short us[TN];
#pragma unroll
            for (int j = 0; j < TN; ++j) us[j] = f2bf(acc[i][j]);
            if constexpr (TN == 8) {
                uint4 pk;
                pk.x = (unsigned)us[0] | ((unsigned)us[1] << 16);
                pk.y = (unsigned)us[2] | ((unsigned)us[3] << 16);
                pk.z = (unsigned)us[4] | ((unsigned)us[5] << 16);
                pk.w = (unsigned)us[6] | ((unsigned)us[7] << 16);
                *(uint4*)(C + (size_t)grow * M + tx * TN) = pk;
            } else {
                uint2 pk;
                pk.x = (unsigned)us[0] | ((unsigned)us[1] << 16);
                pk.y = (unsigned)us[2] | ((unsigned)us[3] << 16);
                *(uint2*)(C + (size_t)grow * M + tx * TN) = pk;
            }
        }
    }
}

// --- CSR aggregation, bf16 gather: one wave per node -----------------------
// out[i] = dinv_i * ( dinv_i*h_i + sum_e dinv_src*h_src ) + b   [+relu]
// M=128: lane reads uint (2 bf16); M=64: lane reads ushort.
template <int M, bool RELU>
__global__ __launch_bounds__(256) void agg_kernel(const unsigned short* __restrict__ h,
                                                  const int* __restrict__ row_ptr,
                                                  const int2* __restrict__ spd,
                                                  const float* __restrict__ dinv,
                                                  const float* __restrict__ bias,
                                                  float* __restrict__ out, int N) {
    int node = __builtin_amdgcn_readfirstlane((int)(blockIdx.x * 4 + (threadIdx.x >> 6)));
    if (node >= N) return;
    int lane = threadIdx.x & 63;
    float di = dinv[node];
    int beg = row_ptr[node];
    int end = row_ptr[node + 1];

    if constexpr (M == 128) {
        const unsigned* hp = (const unsigned*)h;  // 2 bf16 per uint
        unsigned hv = hp[node * 64 + lane];
        float ax = di * bf_lo(hv), ay = di * bf_hi(hv);
        int j = beg;
        for (; j + 3 < end; j += 4) {
            int2 e0 = spd[j], e1 = spd[j + 1], e2 = spd[j + 2], e3 = spd[j + 3];
            unsigned v0 = hp[e0.x * 64 + lane];
            unsigned v1 = hp[e1.x * 64 + lane];
            unsigned v2 = hp[e2.x * 64 + lane];
            unsigned v3 = hp[e3.x * 64 + lane];
            float d0 = __int_as_float(e0.y), d1 = __int_as_float(e1.y);
            float d2 = __int_as_float(e2.y), d3 = __int_as_float(e3.y);
            ax += d0 * bf_lo(v0) + d1 * bf_lo(v1) + d2 * bf_lo(v2) + d3 * bf_lo(v3);
            ay += d0 * bf_hi(v0) + d1 * bf_hi(v1) + d2 * bf_hi(v2) + d3 * bf_hi(v3);
        }
        for (; j < end; ++j) {
            int2 e = spd[j];
            unsigned v = hp[e.x * 64 + lane];
            float ds = __int_as_float(e.y);
            ax += ds * bf_lo(v);
            ay += ds * bf_hi(v);
        }
        ax = ax * di + bias[2 * lane];
        ay = ay * di + bias[2 * lane + 1];
        if (RELU) { ax = fmaxf(ax, 0.f); ay = fmaxf(ay, 0.f); }
        ((float2*)out)[node * 64 + lane] = make_float2(ax, ay);
    } else {  // M == 64: one bf16 per lane
        float acc = di * __uint_as_float((unsigned)h[node * 64 + lane] << 16);
        int j = beg;
        for (; j + 3 < end; j += 4) {
            int2 e0 = spd[j], e1 = spd[j + 1], e2 = spd[j + 2], e3 = spd[j + 3];
            float v0 = __uint_as_float((unsigned)h[e0.x * 64 + lane] << 16);
            float v1 = __uint_as_float((unsigned)h[e1.x * 64 + lane] << 16);
            float v2 = __uint_as_float((unsigned)h[e2.x * 64 + lane] << 16);
            float v3 = __uint_as_float((unsigned)h[e3.x * 64 + lane] << 16);
            acc += __int_as_float(e0.y) * v0 + __int_as_float(e1.y) * v1 +
                   __int_as_float(e2.y) * v2 + __int_as_float(e3.y) * v3;
        }
        for (; j < end; ++j) {
            int2 e = spd[j];
            acc += __int_as_float(e.y) * __uint_as_float((unsigned)h[e.x * 64 + lane] << 16);
        }
        acc = acc * di + bias[lane];
        if (RELU) acc = fmaxf(acc, 0.f);
        out[node * 64 + lane] = acc;
    }
}

extern "C" void kernel_launch(void* const* d_in, const int* in_sizes, int n_in,
                              void* d_out, int out_size, void* d_ws, size_t ws_size,
                              hipStream_t stream) {
    const float* x = (const float*)d_in[0];
    const int* eidx = (const int*)d_in[1];
    const float* W1 = (const float*)d_in[2];
    const float* b1 = (const float*)d_in[3];
    const float* W2 = (const float*)d_in[4];
    const float* b2 = (const float*)d_in[5];
    float* out = (float*)d_out;

    const int N = in_sizes[0] / 128;
    const int E = in_sizes[1] / 2;
    const int* src = eidx;
    const int* dst = eidx + E;

    char* ws = (char*)d_ws;
    size_t off = 0;
    auto alloc = [&](size_t bytes) -> char* {
        char* p = ws + off;
        off = (off + bytes + 255) & ~(size_t)255;
        return p;
    };
    int* cnt = (int*)alloc((size_t)N * 4);
    int* fill = (int*)alloc((size_t)N * 4);
    int* row_ptr = (int*)alloc((size_t)(N + 1) * 4);
    int* blksum = (int*)alloc(256 * 4);
    int2* spd = (int2*)alloc((size_t)E * 8);
    float* dinv = (float*)alloc((size_t)N * 4);
    unsigned short* h1 = (unsigned short*)alloc((size_t)N * 128 * 2);  // bf16
    float* z1 = (float*)alloc((size_t)N * 128 * 4);                    // fp32
    unsigned short* h2 = (unsigned short*)alloc((size_t)N * 64 * 2);   // bf16

    const int nbN = (N + 255) / 256;
    const int nbE = (E + 255) / 256;

    zero2_kernel<<<nbN, 256, 0, stream>>>(cnt, fill, N);
    count_kernel<<<nbE, 256, 0, stream>>>(dst, cnt, E);
    scan1_kernel<<<nbN, 256, 0, stream>>>(cnt, row_ptr, blksum, dinv, N);
    scan2_kernel<<<1, 256, 0, stream>>>(blksum, nbN);
    scan3_kernel<<<nbN, 256, 0, stream>>>(row_ptr, blksum, N, E);
    scatter_kernel<<<nbE, 256, 0, stream>>>(src, dst, row_ptr, dinv, fill, spd, E);

    const int gb = (N + 63) / 64;
    gemm_kernel<128><<<gb, 256, 0, stream>>>(x, W1, h1, N);
    agg_kernel<128, true><<<(N + 3) / 4, 256, 0, stream>>>(h1, row_ptr, spd, dinv, b1, z1, N);
    gemm_kernel<64><<<gb, 256, 0, stream>>>(z1, W2, h2, N);
    agg_kernel<64, false><<<(N + 3) / 4, 256, 0, stream>>>(h2, row_ptr, spd, dinv, b2, out, N);
}

// Round 3
// 233.101 us; speedup vs baseline: 1.3841x; 1.1566x over previous
//
#include <hip/hip_runtime.h>
#include <hip/hip_bf16.h>

// ---------------------------------------------------------------------------
// 2-layer GCN on MI355X, round 3.
//   - CSR build: count atomic RETURNS the slot (no second atomic pass);
//     scatter is atomic-free with a 4 B payload (src only)
//   - dinv folded into GEMM epilogue: g = dinv_row * (A @ W)  (bf16)
//   - agg: out_i = dinv_i * (g_i + sum_{e->i} g_src) + b ; pure adds, unroll 8
// ---------------------------------------------------------------------------

__device__ __forceinline__ float bf_lo(unsigned u) { return __uint_as_float(u << 16); }
__device__ __forceinline__ float bf_hi(unsigned u) { return __uint_as_float(u & 0xffff0000u); }
__device__ __forceinline__ unsigned short f2bf(float f) {
    return (unsigned short)(__bfloat16_as_ushort(__float2bfloat16(f)));
}

__global__ __launch_bounds__(256) void zero_kernel(int* __restrict__ a, int n) {
    int i = blockIdx.x * 256 + threadIdx.x;
    if (i < n) a[i] = 0;
}

// count in-degree; atomic return value IS the CSR slot for this edge
__global__ __launch_bounds__(256) void count_kernel(const int* __restrict__ dst,
                                                    int* __restrict__ cnt,
                                                    int* __restrict__ eslot, int E) {
    int e = blockIdx.x * 256 + threadIdx.x;
    if (e < E) eslot[e] = atomicAdd(&cnt[dst[e]], 1);
}

// exclusive scan pass 1 + fused dinv = rsqrt(deg+1)
__global__ __launch_bounds__(256) void scan1_kernel(const int* __restrict__ cnt,
                                                    int* __restrict__ row_ptr,
                                                    int* __restrict__ blksum,
                                                    float* __restrict__ dinv, int N) {
    __shared__ int sm[256];
    int i = blockIdx.x * 256 + threadIdx.x;
    int v = (i < N) ? cnt[i] : 0;
    if (i < N) dinv[i] = rsqrtf((float)(v + 1));
    sm[threadIdx.x] = v;
    __syncthreads();
    for (int off = 1; off < 256; off <<= 1) {
        int t = (threadIdx.x >= off) ? sm[threadIdx.x - off] : 0;
        __syncthreads();
        sm[threadIdx.x] += t;
        __syncthreads();
    }
    if (i < N) row_ptr[i] = sm[threadIdx.x] - v;
    if (threadIdx.x == 255) blksum[blockIdx.x] = sm[255];
}

__global__ __launch_bounds__(256) void scan2_kernel(int* __restrict__ blksum, int nb) {
    __shared__ int sm[256];
    int i = threadIdx.x;
    int v = (i < nb) ? blksum[i] : 0;
    sm[i] = v;
    __syncthreads();
    for (int off = 1; off < 256; off <<= 1) {
        int t = (i >= off) ? sm[i - off] : 0;
        __syncthreads();
        sm[i] += t;
        __syncthreads();
    }
    if (i < nb) blksum[i] = sm[i] - v;
}

__global__ __launch_bounds__(256) void scan3_kernel(int* __restrict__ row_ptr,
                                                    const int* __restrict__ blksum,
                                                    int N, int E) {
    int i = blockIdx.x * 256 + threadIdx.x;
    if (i < N) row_ptr[i] += blksum[blockIdx.x];
    if (i == 0) row_ptr[N] = E;
}

// atomic-free scatter: slot precomputed by count_kernel
__global__ __launch_bounds__(256) void scatter_kernel(const int* __restrict__ src,
                                                      const int* __restrict__ dst,
                                                      const int* __restrict__ row_ptr,
                                                      const int* __restrict__ eslot,
                                                      int* __restrict__ ssrc, int E) {
    int e = blockIdx.x * 256 + threadIdx.x;
    if (e < E) {
        int p = row_ptr[dst[e]] + eslot[e];
        ssrc[p] = src[e];
    }
}

// --- fp32 GEMM + dinv scale: C[N,M](bf16) = dinv[row] * (A[N,128] @ W[128,M])
// 64-row tile, 256 threads: tx=tid&15 owns M/16 cols, ty=tid>>4 owns 4 rows.
template <int M>
__global__ __launch_bounds__(256) void gemm_kernel(const float* __restrict__ A,
                                                   const float* __restrict__ W,
                                                   const float* __restrict__ dinv,
                                                   unsigned short* __restrict__ C,
                                                   int N) {
    constexpr int K = 128, KC = 32, TN = M / 16;
    __shared__ float As[64][33];
    __shared__ float Bs[KC][M];

    int tid = threadIdx.x;
    int tx = tid & 15;
    int ty = tid >> 4;
    int row0 = blockIdx.x * 64;

    float acc[4][TN];
#pragma unroll
    for (int i = 0; i < 4; ++i)
#pragma unroll
        for (int j = 0; j < TN; ++j) acc[i][j] = 0.f;

    for (int kc = 0; kc < K; kc += KC) {
#pragma unroll
        for (int f = 0; f < 2; ++f) {
            int q = tid + 256 * f;
            int r = q >> 3;
            int kq = (q & 7) << 2;
            int grow = row0 + r;
            float4 v = make_float4(0.f, 0.f, 0.f, 0.f);
            if (grow < N) v = *(const float4*)(A + (size_t)grow * K + kc + kq);
            As[r][kq + 0] = v.x;
            As[r][kq + 1] = v.y;
            As[r][kq + 2] = v.z;
            As[r][kq + 3] = v.w;
        }
        constexpr int BQ = KC * M / 4;
#pragma unroll
        for (int f = 0; f < BQ / 256; ++f) {
            int q = tid + 256 * f;
            int r = q / (M / 4);
            int c4 = (q % (M / 4)) << 2;
            *(float4*)(&Bs[r][c4]) = *(const float4*)(W + (size_t)(kc + r) * M + c4);
        }
        __syncthreads();

#pragma unroll
        for (int k = 0; k < KC; ++k) {
            float a[4], b[TN];
#pragma unroll
            for (int i = 0; i < 4; ++i) a[i] = As[ty * 4 + i][k];
#pragma unroll
            for (int j = 0; j < TN; ++j) b[j] = Bs[k][tx * TN + j];
#pragma unroll
            for (int i = 0; i < 4; ++i)
#pragma unroll
                for (int j = 0; j < TN; ++j) acc[i][j] += a[i] * b[j];
        }
        __syncthreads();
    }

#pragma unroll
    for (int i = 0; i < 4; ++i) {
        int grow = row0 + ty * 4 + i;
        if (grow < N) {
            float dv = dinv[grow];
            unsigned short us[TN];
#pragma unroll
            for (int j = 0; j < TN; ++j) us[j] = f2bf(acc[i][j] * dv);
            if constexpr (TN == 8) {
                uint4 pk;
                pk.x = (unsigned)us[0] | ((unsigned)us[1] << 16);
                pk.y = (unsigned)us[2] | ((unsigned)us[3] << 16);
                pk.z = (unsigned)us[4] | ((unsigned)us[5] << 16);
                pk.w = (unsigned)us[6] | ((unsigned)us[7] << 16);
                *(uint4*)(C + (size_t)grow * M + tx * TN) = pk;
            } else {
                uint2 pk;
                pk.x = (unsigned)us[0] | ((unsigned)us[1] << 16);
                pk.y = (unsigned)us[2] | ((unsigned)us[3] << 16);
                *(uint2*)(C + (size_t)grow * M + tx * TN) = pk;
            }
        }
    }
}

// --- CSR aggregation (pre-scaled g): one wave per node ---------------------
// out[i] = dinv_i * ( g_i + sum_{e: dst=i} g_src ) + b   [+relu]
template <int M, bool RELU>
__global__ __launch_bounds__(256) void agg_kernel(const unsigned short* __restrict__ g,
                                                  const int* __restrict__ row_ptr,
                                                  const int* __restrict__ ssrc,
                                                  const float* __restrict__ dinv,
                                                  const float* __restrict__ bias,
                                                  float* __restrict__ out, int N) {
    int node = __builtin_amdgcn_readfirstlane((int)(blockIdx.x * 4 + (threadIdx.x >> 6)));
    if (node >= N) return;
    int lane = threadIdx.x & 63;
    float di = dinv[node];
    int beg = row_ptr[node];
    int end = row_ptr[node + 1];

    if constexpr (M == 128) {
        const unsigned* hp = (const unsigned*)g;  // 2 bf16 per uint
        unsigned hv = hp[node * 64 + lane];
        float ax0 = bf_lo(hv), ay0 = bf_hi(hv);
        float ax1 = 0.f, ay1 = 0.f;
        int j = beg;
        for (; j + 7 < end; j += 8) {
            int s0 = ssrc[j + 0], s1 = ssrc[j + 1], s2 = ssrc[j + 2], s3 = ssrc[j + 3];
            int s4 = ssrc[j + 4], s5 = ssrc[j + 5], s6 = ssrc[j + 6], s7 = ssrc[j + 7];
            unsigned v0 = hp[s0 * 64 + lane], v1 = hp[s1 * 64 + lane];
            unsigned v2 = hp[s2 * 64 + lane], v3 = hp[s3 * 64 + lane];
            unsigned v4 = hp[s4 * 64 + lane], v5 = hp[s5 * 64 + lane];
            unsigned v6 = hp[s6 * 64 + lane], v7 = hp[s7 * 64 + lane];
            ax0 += bf_lo(v0) + bf_lo(v1) + bf_lo(v2) + bf_lo(v3);
            ax1 += bf_lo(v4) + bf_lo(v5) + bf_lo(v6) + bf_lo(v7);
            ay0 += bf_hi(v0) + bf_hi(v1) + bf_hi(v2) + bf_hi(v3);
            ay1 += bf_hi(v4) + bf_hi(v5) + bf_hi(v6) + bf_hi(v7);
        }
        for (; j + 3 < end; j += 4) {
            int s0 = ssrc[j + 0], s1 = ssrc[j + 1], s2 = ssrc[j + 2], s3 = ssrc[j + 3];
            unsigned v0 = hp[s0 * 64 + lane], v1 = hp[s1 * 64 + lane];
            unsigned v2 = hp[s2 * 64 + lane], v3 = hp[s3 * 64 + lane];
            ax0 += bf_lo(v0) + bf_lo(v1);
            ax1 += bf_lo(v2) + bf_lo(v3);
            ay0 += bf_hi(v0) + bf_hi(v1);
            ay1 += bf_hi(v2) + bf_hi(v3);
        }
        for (; j < end; ++j) {
            unsigned v = hp[ssrc[j] * 64 + lane];
            ax0 += bf_lo(v);
            ay0 += bf_hi(v);
        }
        float ax = (ax0 + ax1) * di + bias[2 * lane];
        float ay = (ay0 + ay1) * di + bias[2 * lane + 1];
        if (RELU) { ax = fmaxf(ax, 0.f); ay = fmaxf(ay, 0.f); }
        ((float2*)out)[node * 64 + lane] = make_float2(ax, ay);
    } else {  // M == 64: one bf16 per lane
        float a0 = __uint_as_float((unsigned)g[node * 64 + lane] << 16);
        float a1 = 0.f;
        int j = beg;
        for (; j + 7 < end; j += 8) {
            int s0 = ssrc[j + 0], s1 = ssrc[j + 1], s2 = ssrc[j + 2], s3 = ssrc[j + 3];
            int s4 = ssrc[j + 4], s5 = ssrc[j + 5], s6 = ssrc[j + 6], s7 = ssrc[j + 7];
            float v0 = __uint_as_float((unsigned)g[s0 * 64 + lane] << 16);
            float v1 = __uint_as_float((unsigned)g[s1 * 64 + lane] << 16);
            float v2 = __uint_as_float((unsigned)g[s2 * 64 + lane] << 16);
            float v3 = __uint_as_float((unsigned)g[s3 * 64 + lane] << 16);
            float v4 = __uint_as_float((unsigned)g[s4 * 64 + lane] << 16);
            float v5 = __uint_as_float((unsigned)g[s5 * 64 + lane] << 16);
            float v6 = __uint_as_float((unsigned)g[s6 * 64 + lane] << 16);
            float v7 = __uint_as_float((unsigned)g[s7 * 64 + lane] << 16);
            a0 += v0 + v1 + v2 + v3;
            a1 += v4 + v5 + v6 + v7;
        }
        for (; j + 3 < end; j += 4) {
            int s0 = ssrc[j + 0], s1 = ssrc[j + 1], s2 = ssrc[j + 2], s3 = ssrc[j + 3];
            float v0 = __uint_as_float((unsigned)g[s0 * 64 + lane] << 16);
            float v1 = __uint_as_float((unsigned)g[s1 * 64 + lane] << 16);
            float v2 = __uint_as_float((unsigned)g[s2 * 64 + lane] << 16);
            float v3 = __uint_as_float((unsigned)g[s3 * 64 + lane] << 16);
            a0 += v0 + v1;
            a1 += v2 + v3;
        }
        for (; j < end; ++j)
            a0 += __uint_as_float((unsigned)g[ssrc[j] * 64 + lane] << 16);
        float acc = (a0 + a1) * di + bias[lane];
        if (RELU) acc = fmaxf(acc, 0.f);
        out[node * 64 + lane] = acc;
    }
}

extern "C" void kernel_launch(void* const* d_in, const int* in_sizes, int n_in,
                              void* d_out, int out_size, void* d_ws, size_t ws_size,
                              hipStream_t stream) {
    const float* x = (const float*)d_in[0];
    const int* eidx = (const int*)d_in[1];
    const float* W1 = (const float*)d_in[2];
    const float* b1 = (const float*)d_in[3];
    const float* W2 = (const float*)d_in[4];
    const float* b2 = (const float*)d_in[5];
    float* out = (float*)d_out;

    const int N = in_sizes[0] / 128;
    const int E = in_sizes[1] / 2;
    const int* src = eidx;
    const int* dst = eidx + E;

    char* ws = (char*)d_ws;
    size_t off = 0;
    auto alloc = [&](size_t bytes) -> char* {
        char* p = ws + off;
        off = (off + bytes + 255) & ~(size_t)255;
        return p;
    };
    int* cnt = (int*)alloc((size_t)N * 4);
    int* row_ptr = (int*)alloc((size_t)(N + 1) * 4);
    int* blksum = (int*)alloc(256 * 4);
    int* eslot = (int*)alloc((size_t)E * 4);
    int* ssrc = (int*)alloc((size_t)E * 4);
    float* dinv = (float*)alloc((size_t)N * 4);
    unsigned short* g1 = (unsigned short*)alloc((size_t)N * 128 * 2);  // bf16
    float* z1 = (float*)alloc((size_t)N * 128 * 4);                    // fp32
    unsigned short* g2 = (unsigned short*)alloc((size_t)N * 64 * 2);   // bf16

    const int nbN = (N + 255) / 256;
    const int nbE = (E + 255) / 256;

    zero_kernel<<<nbN, 256, 0, stream>>>(cnt, N);
    count_kernel<<<nbE, 256, 0, stream>>>(dst, cnt, eslot, E);
    scan1_kernel<<<nbN, 256, 0, stream>>>(cnt, row_ptr, blksum, dinv, N);
    scan2_kernel<<<1, 256, 0, stream>>>(blksum, nbN);
    scan3_kernel<<<nbN, 256, 0, stream>>>(row_ptr, blksum, N, E);
    scatter_kernel<<<nbE, 256, 0, stream>>>(src, dst, row_ptr, eslot, ssrc, E);

    const int gb = (N + 63) / 64;
    gemm_kernel<128><<<gb, 256, 0, stream>>>(x, W1, dinv, g1, N);
    agg_kernel<128, true><<<(N + 3) / 4, 256, 0, stream>>>(g1, row_ptr, ssrc, dinv, b1, z1, N);
    gemm_kernel<64><<<gb, 256, 0, stream>>>(z1, W2, dinv, g2, N);
    agg_kernel<64, false><<<(N + 3) / 4, 256, 0, stream>>>(g2, row_ptr, ssrc, dinv, b2, out, N);
}